// Round 9
// baseline (373.722 us; speedup 1.0000x reference)
//
#include <hip/hip_runtime.h>

#define N_NODES 100000
#define N_EDGES 3200000
#define R_REL   8
#define C_IN    128
#define HID     64
#define WCOLS   576   // 8 relations * 64 + 64 (root slot)

// counting-sort parameters
#define NBUCK 500     // dst buckets
#define NPB   200     // nodes per bucket (500*200 = N)
#define NBLK  256     // edge chunks (runs: CHUNK/NBUCK = 25 edges = 100 B)
#define CHUNK 12500   // E / NBLK (exact)
#define NCELL (NBUCK * NBLK)   // 128000
#define BCAP  7424    // bucket LDS staging cap (mean 6400, +12.8 sigma)
#define GEMM1_BLKS 391         // ceil(N / 256)

typedef __attribute__((ext_vector_type(8))) short  short8;
typedef __attribute__((ext_vector_type(4))) float  float4v;

__device__ __forceinline__ float bf2f(unsigned short u) {
    union { unsigned int i; float f; } v; v.i = ((unsigned int)u) << 16; return v.f;
}
__device__ __forceinline__ unsigned short f2bf(float f) {
    union { float f; unsigned int i; } v; v.f = f;
    unsigned int r = v.i + 0x7FFFu + ((v.i >> 16) & 1u);   // RNE
    return (unsigned short)(r >> 16);
}
__device__ __forceinline__ float rl_f(float v, int j) {
    union { float f; int i; } a, b; a.f = v;
    b.i = __builtin_amdgcn_readlane(a.i, j);
    return b.f;
}

// exclusive scan of v across 1024 threads via shfl wave-scans (3 barriers).
__device__ __forceinline__ int block_exscan_1024(int v, int tid, int* wsum, int* tot) {
    __syncthreads();                       // protect wsum reuse
    const int lane = tid & 63, wid = tid >> 6;
    int s = v;
#pragma unroll
    for (int d = 1; d < 64; d <<= 1) {
        int t = __shfl_up(s, d, 64);
        if (lane >= d) s += t;
    }
    if (lane == 63) wsum[wid] = s;
    __syncthreads();
    if (wid == 0) {
        int ws = (lane < 16) ? wsum[lane] : 0;
#pragma unroll
        for (int d = 1; d < 16; d <<= 1) {
            int t = __shfl_up(ws, d, 64);
            if (lane >= d) ws += t;
        }
        if (lane < 16) wsum[lane] = ws;    // inclusive wave partials
    }
    __syncthreads();
    int wexcl = (wid == 0) ? 0 : wsum[wid - 1];
    if (tot) *tot = wsum[15];
    return wexcl + s - v;
}

// ---------------- weight prep (f32 -> bf16, concatenated+transposed) ----------
__global__ void prep_wcat(const float* __restrict__ W1,
                          const float* __restrict__ root1,
                          const float* __restrict__ W2,
                          const float* __restrict__ root2,
                          unsigned short* __restrict__ BT1,
                          unsigned short* __restrict__ BT2) {
    int idx = blockIdx.x * 256 + threadIdx.x;
    const int T1 = WCOLS * C_IN;          // 73728
    const int T2 = WCOLS * HID;           // 36864
    if (idx < T1) {
        int c = idx / C_IN, k = idx % C_IN;
        float v;
        if (c < 512) { int r = c >> 6, h = c & 63; v = W1[r * (C_IN * 64) + k * 64 + h]; }
        else         { v = root1[k * 64 + (c - 512)]; }
        BT1[idx] = f2bf(v);
    } else if (idx < T1 + T2) {
        int j = idx - T1;
        int c = j / HID, k = j % HID;
        float v;
        if (c < 512) { int r = c >> 6, h = c & 63; v = W2[r * (HID * 64) + k * 64 + h]; }
        else         { v = root2[k * 64 + (c - 512)]; }
        BT2[j] = f2bf(v);
    }
}

// ---------------- fused sort + gemm1 (independent DAG branches overlap) ------
// Block roles interleaved by parity so sort (latency-bound) and gemm1
// (write-BW-bound) co-reside on CUs at any occupancy.
struct SortMem {
    int cnt[NBUCK], cur[NBUCK], wsum[16];
    unsigned int sedge[CHUNK];                 // 54.1 KB total
};
struct GemmMem {
    unsigned short Blds[2][64 * 136];          // dbuf B panel, 34.8 KB
    unsigned short stage[16][1024];            // 32 KB
};

__device__ __forceinline__ void sort_body(char* smem, int blk,
        const int* __restrict__ src, const int* __restrict__ dst,
        const int* __restrict__ et, unsigned int* __restrict__ esort,
        int* __restrict__ bcountT, int* __restrict__ lstartT) {
    SortMem* sm = (SortMem*)smem;
    const int tid = threadIdx.x;
    const int e0 = blk * CHUNK;

    for (int i = tid; i < NBUCK; i += 1024) sm->cnt[i] = 0;
    __syncthreads();
    for (int i = tid; i < CHUNK; i += 1024)
        atomicAdd(&sm->cnt[dst[e0 + i] / NPB], 1);
    __syncthreads();

    int v = (tid < NBUCK) ? sm->cnt[tid] : 0;
    int ex = block_exscan_1024(v, tid, sm->wsum, nullptr);
    if (tid < NBUCK) {
        sm->cur[tid] = ex;
        bcountT[blk * NBUCK + tid] = v;
        lstartT[blk * NBUCK + tid] = ex;
    }
    __syncthreads();     // cur stable before scatter atomics

    for (int i = tid; i < CHUNK; i += 1024) {
        int d = dst[e0 + i];
        int b = d / NPB;
        int pos = atomicAdd(&sm->cur[b], 1);
        sm->sedge[pos] = ((unsigned int)src[e0 + i] << 11) |
                         ((unsigned int)(d - b * NPB) << 3) | (unsigned int)et[e0 + i];
    }
    __syncthreads();
    for (int i = tid; i < CHUNK; i += 1024) esort[e0 + i] = sm->sedge[i];
}

__device__ __forceinline__ void gemm1_body(char* smem, int gblk,
        const float* __restrict__ A, const unsigned short* __restrict__ BT,
        unsigned short* __restrict__ Out, int nrows) {
    GemmMem* gm = (GemmMem*)smem;
    const int tid = threadIdx.x;
    const int wave = tid >> 6, lane = tid & 63;
    const int l15 = lane & 15, quad = lane >> 4;
    const int rowbase = gblk * 256 + wave * 16;
    int arow = rowbase + l15;
    if (arow >= nrows) arow = nrows - 1;

    short8 afrag[4];
#pragma unroll
    for (int ks = 0; ks < 4; ++ks) {
        const float* p = A + (size_t)arow * C_IN + ks * 32 + quad * 8;
        float4v u0 = *(const float4v*)p;
        float4v u1 = *(const float4v*)(p + 4);
        short8 f;
        f[0] = (short)f2bf(u0[0]); f[1] = (short)f2bf(u0[1]);
        f[2] = (short)f2bf(u0[2]); f[3] = (short)f2bf(u0[3]);
        f[4] = (short)f2bf(u1[0]); f[5] = (short)f2bf(u1[1]);
        f[6] = (short)f2bf(u1[2]); f[7] = (short)f2bf(u1[3]);
        afrag[ks] = f;
    }

    {   // preload chunk 0 (1024 threads = 1024 x 16B vectors, one shot)
        int r = tid >> 4, c = (tid & 15) * 8;
        *(uint4*)&gm->Blds[0][r * 136 + c] = *(const uint4*)(BT + r * C_IN + c);
    }
    __syncthreads();

    int cur = 0;
    for (int chunk = 0; chunk < 9; ++chunk) {
        uint4 p0;
        if (chunk < 8) {
            const unsigned short* src = BT + (size_t)(chunk + 1) * 64 * C_IN;
            p0 = *(const uint4*)(src + (tid >> 4) * C_IN + (tid & 15) * 8);
        }

        float4v acc[4];
#pragma unroll
        for (int ct = 0; ct < 4; ++ct) { acc[ct][0] = 0.f; acc[ct][1] = 0.f; acc[ct][2] = 0.f; acc[ct][3] = 0.f; }
#pragma unroll
        for (int ct = 0; ct < 4; ++ct)
#pragma unroll
            for (int ks = 0; ks < 4; ++ks) {
                short8 bfrag = *(const short8*)(&gm->Blds[cur][(ct * 16 + l15) * 136 + ks * 32 + quad * 8]);
                acc[ct] = __builtin_amdgcn_mfma_f32_16x16x32_bf16(afrag[ks], bfrag, acc[ct], 0, 0, 0);
            }

#pragma unroll
        for (int ct = 0; ct < 4; ++ct)
#pragma unroll
            for (int r = 0; r < 4; ++r)
                gm->stage[wave][(quad * 4 + r) * 64 + ct * 16 + l15] = f2bf(acc[ct][r]);
        {
            int r = lane >> 2, j = lane & 3;
            int orow = rowbase + r;
            if (orow < nrows) {
#pragma unroll
                for (int p = 0; p < 2; ++p) {
                    int c0 = (j + p * 4) * 8;
                    uint4 v = *(const uint4*)&gm->stage[wave][r * 64 + c0];
                    *(uint4*)(Out + (size_t)orow * WCOLS + chunk * 64 + c0) = v;
                }
            }
        }

        if (chunk < 8) {
            *(uint4*)&gm->Blds[cur ^ 1][(tid >> 4) * 136 + (tid & 15) * 8] = p0;
            cur ^= 1;
        }
        __syncthreads();
    }
}

__global__ __launch_bounds__(1024)
void sort_gemm1(const int* __restrict__ src, const int* __restrict__ dst,
                const int* __restrict__ et,
                unsigned int* __restrict__ esort,
                int* __restrict__ bcountT, int* __restrict__ lstartT,
                const float* __restrict__ x, const unsigned short* __restrict__ BT1,
                unsigned short* __restrict__ xW) {
    __shared__ __align__(16) char smem[sizeof(GemmMem) > sizeof(SortMem) ?
                                       sizeof(GemmMem) : sizeof(SortMem)];
    const int bx = blockIdx.x;
    if (bx < 2 * NBLK) {
        if (!(bx & 1)) sort_body(smem, bx >> 1, src, dst, et, esort, bcountT, lstartT);
        else           gemm1_body(smem, bx >> 1, x, BT1, xW, N_NODES);
    } else {
        gemm1_body(smem, NBLK + (bx - 2 * NBLK), x, BT1, xW, N_NODES);
    }
}

// ---------------- bucket_build: 2 blocks/CU, search-free, wave scans ---------
__global__ __launch_bounds__(1024)
void bucket_build(const unsigned int* __restrict__ esort,
                  const int* __restrict__ bcountT, const int* __restrict__ lstartT,
                  unsigned int* __restrict__ elist,
                  int* __restrict__ rowstart8) {
    __shared__ int   cnt[2048], cur[2048];              // 16384 B
    __shared__ int   rlen_s[NBLK], rpos[NBLK], rloff[NBLK], wsum[16];  // 3136 B
    __shared__ unsigned int sedge[BCAP];                // 29696 B
    __shared__ unsigned int selist[BCAP];               // 29696 B  (total ~77 KB)

    const int b = blockIdx.x, tid = threadIdx.x;

    for (int i = tid; i < 2048; i += 1024) cnt[i] = 0;
    int myrl = 0, myls = 0;
    if (tid < NBLK) {
        myrl = bcountT[tid * NBUCK + b];
        myls = lstartT[tid * NBUCK + b];
        rlen_s[tid] = myrl;
        rpos[tid] = tid * CHUNK + myls;
    }

    int total;
    int rex = block_exscan_1024(myrl, tid, wsum, &total);
    if (tid < NBLK) rloff[tid] = rex;

    int seg0;
    (void)block_exscan_1024(myls, tid, wsum, &seg0);
    __syncthreads();
    const bool fits = (total <= BCAP);

    {   // pass 1: run-assigned (4 thr/run), stage + histogram, no search
        const int run = tid >> 2, sub = tid & 3;
        const int len = rlen_s[run], lp = rpos[run], ro = rloff[run];
        for (int k = sub; k < len; k += 4) {
            unsigned int e = esort[lp + k];
            if (fits) sedge[ro + k] = e;
            atomicAdd(&cnt[(int)((e >> 3) & 255u) * 8 + (int)(e & 7u)], 1);
        }
    }
    __syncthreads();

    int base = tid * 2;
    int c0 = cnt[base], c1 = cnt[base + 1];
    int ex2 = block_exscan_1024(c0 + c1, tid, wsum, nullptr);
    cur[base] = ex2; cur[base + 1] = ex2 + c0;
    __syncthreads();

    for (int i = tid; i < NPB * 8; i += 1024)
        rowstart8[(b * NPB) * 8 + i] = seg0 + cur[i];
    if (b == NBUCK - 1 && tid == 0) rowstart8[N_NODES * 8] = N_EDGES;
    __syncthreads();

    if (fits) {
        for (int i = tid; i < total; i += 1024) {
            unsigned int e = sedge[i];
            int r = (int)(e & 7u);
            int j = (int)((e >> 3) & 255u) * 8 + r;
            int p = atomicAdd(&cur[j], 1);
            selist[p] = (e >> 11) * WCOLS + (unsigned int)(r * 64);
        }
        __syncthreads();
        for (int i = tid; i < total; i += 1024)
            elist[seg0 + i] = selist[i];
    } else {
        const int run = tid >> 2, sub = tid & 3;
        const int len = rlen_s[run], lp = rpos[run];
        for (int k = sub; k < len; k += 4) {
            unsigned int e = esort[lp + k];
            int r = (int)(e & 7u);
            int j = (int)((e >> 3) & 255u) * 8 + r;
            int p = atomicAdd(&cur[j], 1);
            elist[seg0 + p] = (e >> 11) * WCOLS + (unsigned int)(r * 64);
        }
    }
}

// ---------------- gemm_l2: hW[N][576] = h[N][64] @ BT2, B fully LDS-resident -
__global__ __launch_bounds__(512)
void gemm_l2(const unsigned short* __restrict__ A,     // h [N][64]
             const unsigned short* __restrict__ BT,    // [576][64]
             unsigned short* __restrict__ Out, int nrows) {
    constexpr int K = HID;              // 64
    constexpr int LDB = K + 8;          // 72
    __shared__ __align__(16) unsigned short Blds[WCOLS * LDB];   // 82.9 KB
    __shared__ __align__(16) unsigned short stage[8][16 * 64];   // 16 KB

    const int wave = threadIdx.x >> 6, lane = threadIdx.x & 63;
    const int l15 = lane & 15, quad = lane >> 4;

    for (int i = threadIdx.x; i < WCOLS * K / 8; i += 512) {
        int c = i >> 3, kv = (i & 7) * 8;
        *(uint4*)&Blds[c * LDB + kv] = *(const uint4*)(BT + c * K + kv);
    }
    __syncthreads();    // the only barrier

    const int ntiles = (nrows + 127) / 128;
    for (int t = blockIdx.x; t < ntiles; t += gridDim.x) {
        const int rowbase = t * 128 + wave * 16;
        int arow = rowbase + l15;
        if (arow >= nrows) arow = nrows - 1;
        short8 afrag[2];
#pragma unroll
        for (int ks = 0; ks < 2; ++ks)
            afrag[ks] = *(const short8*)(A + (size_t)arow * K + ks * 32 + quad * 8);

        for (int chunk = 0; chunk < 9; ++chunk) {
            float4v acc[4];
#pragma unroll
            for (int ct = 0; ct < 4; ++ct) { acc[ct][0] = 0.f; acc[ct][1] = 0.f; acc[ct][2] = 0.f; acc[ct][3] = 0.f; }
#pragma unroll
            for (int ct = 0; ct < 4; ++ct)
#pragma unroll
                for (int ks = 0; ks < 2; ++ks) {
                    short8 bfrag = *(const short8*)(&Blds[(chunk * 64 + ct * 16 + l15) * LDB + ks * 32 + quad * 8]);
                    acc[ct] = __builtin_amdgcn_mfma_f32_16x16x32_bf16(afrag[ks], bfrag, acc[ct], 0, 0, 0);
                }

#pragma unroll
            for (int ct = 0; ct < 4; ++ct)
#pragma unroll
                for (int r = 0; r < 4; ++r)
                    stage[wave][(quad * 4 + r) * 64 + ct * 16 + l15] = f2bf(acc[ct][r]);
            {
                int r = lane >> 2, j = lane & 3;
                int orow = rowbase + r;
                if (orow < nrows) {
#pragma unroll
                    for (int p = 0; p < 2; ++p) {
                        int c0 = (j + p * 4) * 8;
                        uint4 v = *(const uint4*)&stage[wave][r * 64 + c0];
                        *(uint4*)(Out + (size_t)orow * WCOLS + chunk * 64 + c0) = v;
                    }
                }
            }
        }
    }
}

// ---------------- fused CSR aggregate + root + bias (+relu) ------------------
template <int MODE>   // 0: relu -> bf16 h ; 1: -> f32 out
__global__ __launch_bounds__(256)
void agg_fused(const unsigned short* __restrict__ XW,
               const unsigned int* __restrict__ elist,
               const int* __restrict__ rowstart8,
               const float* __restrict__ bias,
               void* __restrict__ outp) {
    const int wave = threadIdx.x >> 6, lane = threadIdx.x & 63;
    const int n = blockIdx.x * 4 + wave;          // grid covers N exactly
    int r9 = 0;
    if (lane < 9) r9 = rowstart8[n * 8 + lane];
    const int b0 = __builtin_amdgcn_readlane(r9, 0);
    const int b1 = __builtin_amdgcn_readlane(r9, 1);
    const int b2 = __builtin_amdgcn_readlane(r9, 2);
    const int b3 = __builtin_amdgcn_readlane(r9, 3);
    const int b4 = __builtin_amdgcn_readlane(r9, 4);
    const int b5 = __builtin_amdgcn_readlane(r9, 5);
    const int b6 = __builtin_amdgcn_readlane(r9, 6);
    const int b7 = __builtin_amdgcn_readlane(r9, 7);
    const int b8 = __builtin_amdgcn_readlane(r9, 8);
    const int beg = b0, end = b8;

    auto invlen = [](int a, int bnd) {
        int l = bnd - a; return 1.0f / (float)(l > 1 ? l : 1);
    };
    const float il0 = invlen(b0, b1), il1 = invlen(b1, b2);
    const float il2 = invlen(b2, b3), il3 = invlen(b3, b4);
    const float il4 = invlen(b4, b5), il5 = invlen(b5, b6);
    const float il6 = invlen(b6, b7), il7 = invlen(b7, b8);

    const unsigned short* XWl = XW + lane;        // fold lane offset into base

    float acc = 0.f;
    int i = beg;
    while (i < end) {
        int m = end - i; if (m > 64) m = 64;
        int idx = i + lane; if (idx >= end) idx = end - 1;
        unsigned int ub = elist[idx];             // offset (coalesced, 1 load / 64 edges)
        float wb = il0;
        wb = (idx >= b1) ? il1 : wb;
        wb = (idx >= b2) ? il2 : wb;
        wb = (idx >= b3) ? il3 : wb;
        wb = (idx >= b4) ? il4 : wb;
        wb = (idx >= b5) ? il5 : wb;
        wb = (idx >= b6) ? il6 : wb;
        wb = (idx >= b7) ? il7 : wb;

        int j = 0;
        for (; j + 16 <= m; j += 16) {
            float vv[16], ww[16];
#pragma unroll
            for (int t = 0; t < 16; ++t) {
                unsigned int u = (unsigned int)__builtin_amdgcn_readlane((int)ub, j + t);
                ww[t] = rl_f(wb, j + t);
                vv[t] = bf2f(XWl[u]);
            }
#pragma unroll
            for (int t = 0; t < 16; ++t) acc += ww[t] * vv[t];
        }
        for (; j + 4 <= m; j += 4) {
            float vv[4], ww[4];
#pragma unroll
            for (int t = 0; t < 4; ++t) {
                unsigned int u = (unsigned int)__builtin_amdgcn_readlane((int)ub, j + t);
                ww[t] = rl_f(wb, j + t);
                vv[t] = bf2f(XWl[u]);
            }
#pragma unroll
            for (int t = 0; t < 4; ++t) acc += ww[t] * vv[t];
        }
        for (; j < m; ++j) {
            unsigned int u = (unsigned int)__builtin_amdgcn_readlane((int)ub, j);
            float w = rl_f(wb, j);
            acc += w * bf2f(XWl[u]);
        }
        i += m;
    }

    float res = acc + bf2f(XW[(size_t)n * WCOLS + 512 + lane]) + bias[lane];
    if (MODE == 0) {
        res = res > 0.f ? res : 0.f;
        ((unsigned short*)outp)[(size_t)n * 64 + lane] = f2bf(res);
    } else {
        ((float*)outp)[(size_t)n * 64 + lane] = res;
    }
}

// ---------------- launch ------------------------------------------------------
extern "C" void kernel_launch(void* const* d_in, const int* in_sizes, int n_in,
                              void* d_out, int out_size, void* d_ws, size_t ws_size,
                              hipStream_t stream) {
    const float* x     = (const float*)d_in[0];
    const int*   eidx  = (const int*)d_in[1];
    const int*   etyp  = (const int*)d_in[2];
    const float* W1    = (const float*)d_in[3];
    const float* root1 = (const float*)d_in[4];
    const float* b1    = (const float*)d_in[5];
    const float* W2    = (const float*)d_in[6];
    const float* root2 = (const float*)d_in[7];
    const float* b2    = (const float*)d_in[8];
    float*       out   = (float*)d_out;

    char* ws = (char*)d_ws;
    size_t off = 0;
    auto alloc = [&](size_t bytes) { char* p = ws + off; off += (bytes + 255) & ~(size_t)255; return p; };

    unsigned short* xW       = (unsigned short*)alloc((size_t)N_NODES * WCOLS * 2); // 115.2 MB (reused as hW)
    unsigned short* h        = (unsigned short*)alloc((size_t)N_NODES * HID * 2);   //  12.8 MB (esort aliases: h written only after bucket consumes esort)
    unsigned int*   elist    = (unsigned int*)alloc((size_t)N_EDGES * 4);           //  12.8 MB
    int*            rowstart8= (int*)alloc(((size_t)N_NODES * 8 + 1) * 4);          //   3.2 MB
    unsigned short* BT1      = (unsigned short*)alloc((size_t)WCOLS * C_IN * 2);
    unsigned short* BT2      = (unsigned short*)alloc((size_t)WCOLS * HID * 2);
    int*            bcountT  = (int*)alloc((size_t)NCELL * 4);                      //   0.5 MB (fresh: xW now live during sort)
    int*            lstartT  = (int*)alloc((size_t)NCELL * 4);                      //   0.5 MB
    // total ~146 MB

    unsigned int* esort = (unsigned int*)h;     // 12.8 MB alias (dead before agg1 writes h)

    const int* srcp = eidx;
    const int* dstp = eidx + N_EDGES;

    prep_wcat<<<(WCOLS * (C_IN + HID) + 255) / 256, 256, 0, stream>>>(W1, root1, W2, root2, BT1, BT2);

    // fused: edge sort (independent) overlapped with layer-1 GEMM
    sort_gemm1<<<2 * NBLK + (GEMM1_BLKS - NBLK), 1024, 0, stream>>>(
        srcp, dstp, etyp, esort, bcountT, lstartT, x, BT1, xW);

    bucket_build<<<NBUCK, 1024, 0, stream>>>(esort, bcountT, lstartT, elist, rowstart8);

    const int agg_grid = N_NODES / 4;            // 25000

    // layer 1 aggregate: xW -> h (bf16, relu)
    agg_fused<0><<<agg_grid, 256, 0, stream>>>(xW, elist, rowstart8, b1, (void*)h);

    // layer 2: h -> hW (reuse xW) -> out (f32)
    gemm_l2<<<256, 512, 0, stream>>>(h, BT2, xW, N_NODES);
    agg_fused<1><<<agg_grid, 256, 0, stream>>>(xW, elist, rowstart8, b2, (void*)out);
}

// Round 10
// 363.359 us; speedup vs baseline: 1.0285x; 1.0285x over previous
//
#include <hip/hip_runtime.h>

#define N_NODES 100000
#define N_EDGES 3200000
#define R_REL   8
#define C_IN    128
#define HID     64
#define WCOLS   576   // 8 relations * 64 + 64 (root slot)

// counting-sort parameters
#define NBUCK 500     // dst buckets
#define NPB   200     // nodes per bucket (500*200 = N)
#define NBLK  256     // edge chunks (runs: CHUNK/NBUCK = 25 edges = 100 B)
#define CHUNK 12500   // E / NBLK (exact)
#define NCELL (NBUCK * NBLK)   // 128000
#define BCAP  7424    // bucket LDS staging cap (mean 6400, +12.8 sigma)
#define PREPC 432     // prep elems per sort block (256*432 = 110592 = WCOLS*(C_IN+HID))

typedef __attribute__((ext_vector_type(8))) short  short8;
typedef __attribute__((ext_vector_type(4))) float  float4v;

__device__ __forceinline__ float bf2f(unsigned short u) {
    union { unsigned int i; float f; } v; v.i = ((unsigned int)u) << 16; return v.f;
}
__device__ __forceinline__ unsigned short f2bf(float f) {
    union { float f; unsigned int i; } v; v.f = f;
    unsigned int r = v.i + 0x7FFFu + ((v.i >> 16) & 1u);   // RNE
    return (unsigned short)(r >> 16);
}
__device__ __forceinline__ float rl_f(float v, int j) {
    union { float f; int i; } a, b; a.f = v;
    b.i = __builtin_amdgcn_readlane(a.i, j);
    return b.f;
}

// exclusive scan of v across 1024 threads via shfl wave-scans (3 barriers).
__device__ __forceinline__ int block_exscan_1024(int v, int tid, int* wsum, int* tot) {
    __syncthreads();                       // protect wsum reuse
    const int lane = tid & 63, wid = tid >> 6;
    int s = v;
#pragma unroll
    for (int d = 1; d < 64; d <<= 1) {
        int t = __shfl_up(s, d, 64);
        if (lane >= d) s += t;
    }
    if (lane == 63) wsum[wid] = s;
    __syncthreads();
    if (wid == 0) {
        int ws = (lane < 16) ? wsum[lane] : 0;
#pragma unroll
        for (int d = 1; d < 16; d <<= 1) {
            int t = __shfl_up(ws, d, 64);
            if (lane >= d) ws += t;
        }
        if (lane < 16) wsum[lane] = ws;    // inclusive wave partials
    }
    __syncthreads();
    int wexcl = (wid == 0) ? 0 : wsum[wid - 1];
    if (tot) *tot = wsum[15];
    return wexcl + s - v;
}

// ---------------- K1: per-block LDS counting sort (+ folded weight prep) -----
__global__ __launch_bounds__(1024)
void edge_sort_local(const int* __restrict__ src, const int* __restrict__ dst,
                     const int* __restrict__ et,
                     const float* __restrict__ W1, const float* __restrict__ root1,
                     const float* __restrict__ W2, const float* __restrict__ root2,
                     unsigned short* __restrict__ BT1, unsigned short* __restrict__ BT2,
                     unsigned int* __restrict__ esort,
                     int* __restrict__ bcountT, int* __restrict__ lstartT) {
    __shared__ int cnt[NBUCK], cur[NBUCK], wsum[16];
    __shared__ unsigned int sedge[CHUNK];               // 50 KB
    const int blk = blockIdx.x, tid = threadIdx.x;
    const int e0 = blk * CHUNK;

    // folded weight prep: 432 elems per block, exact cover of 110592
    if (tid < PREPC) {
        int idx = blk * PREPC + tid;
        const int T1 = WCOLS * C_IN;          // 73728
        if (idx < T1) {
            int c = idx / C_IN, k = idx % C_IN;
            float v;
            if (c < 512) { int r = c >> 6, h = c & 63; v = W1[r * (C_IN * 64) + k * 64 + h]; }
            else         { v = root1[k * 64 + (c - 512)]; }
            BT1[idx] = f2bf(v);
        } else {
            int j = idx - T1;
            int c = j / HID, k = j % HID;
            float v;
            if (c < 512) { int r = c >> 6, h = c & 63; v = W2[r * (HID * 64) + k * 64 + h]; }
            else         { v = root2[k * 64 + (c - 512)]; }
            BT2[j] = f2bf(v);
        }
    }

    for (int i = tid; i < NBUCK; i += 1024) cnt[i] = 0;
    __syncthreads();
    for (int i = tid; i < CHUNK; i += 1024)
        atomicAdd(&cnt[dst[e0 + i] / NPB], 1);
    __syncthreads();

    int v = (tid < NBUCK) ? cnt[tid] : 0;
    int ex = block_exscan_1024(v, tid, wsum, nullptr);
    if (tid < NBUCK) {
        cur[tid] = ex;
        bcountT[blk * NBUCK + tid] = v;
        lstartT[blk * NBUCK + tid] = ex;
    }
    __syncthreads();     // cur stable before scatter atomics

    for (int i = tid; i < CHUNK; i += 1024) {
        int d = dst[e0 + i];
        int b = d / NPB;
        int pos = atomicAdd(&cur[b], 1);
        sedge[pos] = ((unsigned int)src[e0 + i] << 11) |
                     ((unsigned int)(d - b * NPB) << 3) | (unsigned int)et[e0 + i];
    }
    __syncthreads();
    for (int i = tid; i < CHUNK; i += 1024) esort[e0 + i] = sedge[i];
}

// ---------------- bucket_build: 2 blocks/CU, search-free, wave scans ---------
__global__ __launch_bounds__(1024)
void bucket_build(const unsigned int* __restrict__ esort,
                  const int* __restrict__ bcountT, const int* __restrict__ lstartT,
                  unsigned int* __restrict__ elist,
                  int* __restrict__ rowstart8) {
    __shared__ int   cnt[2048], cur[2048];              // 16384 B
    __shared__ int   rlen_s[NBLK], rpos[NBLK], rloff[NBLK], wsum[16];  // 3136 B
    __shared__ unsigned int sedge[BCAP];                // 29696 B
    __shared__ unsigned int selist[BCAP];               // 29696 B  (total ~77 KB)

    const int b = blockIdx.x, tid = threadIdx.x;

    for (int i = tid; i < 2048; i += 1024) cnt[i] = 0;
    int myrl = 0, myls = 0;
    if (tid < NBLK) {
        myrl = bcountT[tid * NBUCK + b];
        myls = lstartT[tid * NBUCK + b];
        rlen_s[tid] = myrl;
        rpos[tid] = tid * CHUNK + myls;
    }

    int total;
    int rex = block_exscan_1024(myrl, tid, wsum, &total);
    if (tid < NBLK) rloff[tid] = rex;

    int seg0;
    (void)block_exscan_1024(myls, tid, wsum, &seg0);
    __syncthreads();
    const bool fits = (total <= BCAP);

    {   // pass 1: run-assigned (4 thr/run), stage + histogram, no search
        const int run = tid >> 2, sub = tid & 3;
        const int len = rlen_s[run], lp = rpos[run], ro = rloff[run];
        for (int k = sub; k < len; k += 4) {
            unsigned int e = esort[lp + k];
            if (fits) sedge[ro + k] = e;
            atomicAdd(&cnt[(int)((e >> 3) & 255u) * 8 + (int)(e & 7u)], 1);
        }
    }
    __syncthreads();

    int base = tid * 2;
    int c0 = cnt[base], c1 = cnt[base + 1];
    int ex2 = block_exscan_1024(c0 + c1, tid, wsum, nullptr);
    cur[base] = ex2; cur[base + 1] = ex2 + c0;
    __syncthreads();

    for (int i = tid; i < NPB * 8; i += 1024)
        rowstart8[(b * NPB) * 8 + i] = seg0 + cur[i];
    if (b == NBUCK - 1 && tid == 0) rowstart8[N_NODES * 8] = N_EDGES;
    __syncthreads();

    if (fits) {
        for (int i = tid; i < total; i += 1024) {
            unsigned int e = sedge[i];
            int r = (int)(e & 7u);
            int j = (int)((e >> 3) & 255u) * 8 + r;
            int p = atomicAdd(&cur[j], 1);
            selist[p] = (e >> 11) * WCOLS + (unsigned int)(r * 64);
        }
        __syncthreads();
        for (int i = tid; i < total; i += 1024)
            elist[seg0 + i] = selist[i];
    } else {
        const int run = tid >> 2, sub = tid & 3;
        const int len = rlen_s[run], lp = rpos[run];
        for (int k = sub; k < len; k += 4) {
            unsigned int e = esort[lp + k];
            int r = (int)(e & 7u);
            int j = (int)((e >> 3) & 255u) * 8 + r;
            int p = atomicAdd(&cur[j], 1);
            elist[seg0 + p] = (e >> 11) * WCOLS + (unsigned int)(r * 64);
        }
    }
}

// ---------------- gemm_l1: xW[N][576] = x[N][128] @ BT1, dbuf B --------------
__global__ __launch_bounds__(512)
void gemm_l1(const float* __restrict__ A,
             const unsigned short* __restrict__ BT,
             unsigned short* __restrict__ Out, int nrows) {
    constexpr int K = C_IN;             // 128
    constexpr int LDB = K + 8;          // 136
    __shared__ __align__(16) unsigned short Blds[2][64 * LDB];  // 34.8 KB
    __shared__ __align__(16) unsigned short stage[8][16 * 64];  // 16 KB

    const int wave = threadIdx.x >> 6, lane = threadIdx.x & 63;
    const int l15 = lane & 15, quad = lane >> 4;
    const int rowbase = blockIdx.x * 128 + wave * 16;
    int arow = rowbase + l15;
    if (arow >= nrows) arow = nrows - 1;

    short8 afrag[4];
#pragma unroll
    for (int ks = 0; ks < 4; ++ks) {
        const float* p = A + (size_t)arow * K + ks * 32 + quad * 8;
        float4v u0 = *(const float4v*)p;
        float4v u1 = *(const float4v*)(p + 4);
        short8 f;
        f[0] = (short)f2bf(u0[0]); f[1] = (short)f2bf(u0[1]);
        f[2] = (short)f2bf(u0[2]); f[3] = (short)f2bf(u0[3]);
        f[4] = (short)f2bf(u1[0]); f[5] = (short)f2bf(u1[1]);
        f[6] = (short)f2bf(u1[2]); f[7] = (short)f2bf(u1[3]);
        afrag[ks] = f;
    }

    for (int i = threadIdx.x; i < 1024; i += 512) {
        int r = i >> 4, c = (i & 15) * 8;
        *(uint4*)&Blds[0][r * LDB + c] = *(const uint4*)(BT + r * K + c);
    }
    __syncthreads();

    int cur = 0;
    for (int chunk = 0; chunk < 9; ++chunk) {
        uint4 p0, p1;
        const int i0 = threadIdx.x, i1 = threadIdx.x + 512;
        if (chunk < 8) {
            const unsigned short* src = BT + (size_t)(chunk + 1) * 64 * K;
            p0 = *(const uint4*)(src + (i0 >> 4) * K + (i0 & 15) * 8);
            p1 = *(const uint4*)(src + (i1 >> 4) * K + (i1 & 15) * 8);
        }

        float4v acc[4];
#pragma unroll
        for (int ct = 0; ct < 4; ++ct) { acc[ct][0] = 0.f; acc[ct][1] = 0.f; acc[ct][2] = 0.f; acc[ct][3] = 0.f; }
#pragma unroll
        for (int ct = 0; ct < 4; ++ct)
#pragma unroll
            for (int ks = 0; ks < 4; ++ks) {
                short8 bfrag = *(const short8*)(&Blds[cur][(ct * 16 + l15) * LDB + ks * 32 + quad * 8]);
                acc[ct] = __builtin_amdgcn_mfma_f32_16x16x32_bf16(afrag[ks], bfrag, acc[ct], 0, 0, 0);
            }

#pragma unroll
        for (int ct = 0; ct < 4; ++ct)
#pragma unroll
            for (int r = 0; r < 4; ++r)
                stage[wave][(quad * 4 + r) * 64 + ct * 16 + l15] = f2bf(acc[ct][r]);
        {
            int r = lane >> 2, j = lane & 3;
            int orow = rowbase + r;
            if (orow < nrows) {
#pragma unroll
                for (int p = 0; p < 2; ++p) {
                    int c0 = (j + p * 4) * 8;
                    uint4 v = *(const uint4*)&stage[wave][r * 64 + c0];
                    *(uint4*)(Out + (size_t)orow * WCOLS + chunk * 64 + c0) = v;
                }
            }
        }

        if (chunk < 8) {
            *(uint4*)&Blds[cur ^ 1][(i0 >> 4) * LDB + (i0 & 15) * 8] = p0;
            *(uint4*)&Blds[cur ^ 1][(i1 >> 4) * LDB + (i1 & 15) * 8] = p1;
            cur ^= 1;
        }
        __syncthreads();
    }
}

// ---------------- gemm_l2 v2: hW[N][576] = h[N][64] @ BT2, per-chunk dbuf ----
// B chunk = 64 cols x 64 K = 8.2 KB; dbuf 16.4 KB + stage 16 KB = 34.8 KB LDS
// -> 4 blocks/CU x 8 waves = 32 waves/CU (was 1 block/CU, 8 waves with the
// 83 KB resident panel). One barrier per chunk. grid 782 (one 128-row tile/blk).
__global__ __launch_bounds__(512)
void gemm_l2(const unsigned short* __restrict__ A,     // h [N][64]
             const unsigned short* __restrict__ BT,    // [576][64]
             unsigned short* __restrict__ Out, int nrows) {
    constexpr int K = HID;              // 64
    constexpr int LDB = K + 8;          // 72
    __shared__ __align__(16) unsigned short Blds[2][64 * LDB];  // 18.4 KB
    __shared__ __align__(16) unsigned short stage[8][16 * 64];  // 16 KB

    const int wave = threadIdx.x >> 6, lane = threadIdx.x & 63;
    const int l15 = lane & 15, quad = lane >> 4;
    const int rowbase = blockIdx.x * 128 + wave * 16;
    int arow = rowbase + l15;
    if (arow >= nrows) arow = nrows - 1;

    short8 afrag[2];
#pragma unroll
    for (int ks = 0; ks < 2; ++ks)
        afrag[ks] = *(const short8*)(A + (size_t)arow * K + ks * 32 + quad * 8);

    {   // preload chunk 0: 512 vectors of 16B, one per thread
        int r = threadIdx.x >> 3, c = (threadIdx.x & 7) * 8;
        *(uint4*)&Blds[0][r * LDB + c] = *(const uint4*)(BT + r * K + c);
    }
    __syncthreads();

    int cur = 0;
    for (int chunk = 0; chunk < 9; ++chunk) {
        uint4 p0;
        if (chunk < 8) {
            const unsigned short* src = BT + (size_t)(chunk + 1) * 64 * K;
            p0 = *(const uint4*)(src + (threadIdx.x >> 3) * K + (threadIdx.x & 7) * 8);
        }

        float4v acc[4];
#pragma unroll
        for (int ct = 0; ct < 4; ++ct) { acc[ct][0] = 0.f; acc[ct][1] = 0.f; acc[ct][2] = 0.f; acc[ct][3] = 0.f; }
#pragma unroll
        for (int ct = 0; ct < 4; ++ct)
#pragma unroll
            for (int ks = 0; ks < 2; ++ks) {
                short8 bfrag = *(const short8*)(&Blds[cur][(ct * 16 + l15) * LDB + ks * 32 + quad * 8]);
                acc[ct] = __builtin_amdgcn_mfma_f32_16x16x32_bf16(afrag[ks], bfrag, acc[ct], 0, 0, 0);
            }

#pragma unroll
        for (int ct = 0; ct < 4; ++ct)
#pragma unroll
            for (int r = 0; r < 4; ++r)
                stage[wave][(quad * 4 + r) * 64 + ct * 16 + l15] = f2bf(acc[ct][r]);
        {
            int r = lane >> 2, j = lane & 3;
            int orow = rowbase + r;
            if (orow < nrows) {
#pragma unroll
                for (int p = 0; p < 2; ++p) {
                    int c0 = (j + p * 4) * 8;
                    uint4 v = *(const uint4*)&stage[wave][r * 64 + c0];
                    *(uint4*)(Out + (size_t)orow * WCOLS + chunk * 64 + c0) = v;
                }
            }
        }

        if (chunk < 8) {
            *(uint4*)&Blds[cur ^ 1][(threadIdx.x >> 3) * LDB + (threadIdx.x & 7) * 8] = p0;
            cur ^= 1;
        }
        __syncthreads();
    }
}

// ---------------- fused CSR aggregate + root + bias (+relu) ------------------
template <int MODE>   // 0: relu -> bf16 h ; 1: -> f32 out
__global__ __launch_bounds__(256)
void agg_fused(const unsigned short* __restrict__ XW,
               const unsigned int* __restrict__ elist,
               const int* __restrict__ rowstart8,
               const float* __restrict__ bias,
               void* __restrict__ outp) {
    const int wave = threadIdx.x >> 6, lane = threadIdx.x & 63;
    const int n = blockIdx.x * 4 + wave;          // grid covers N exactly
    int r9 = 0;
    if (lane < 9) r9 = rowstart8[n * 8 + lane];
    const int b0 = __builtin_amdgcn_readlane(r9, 0);
    const int b1 = __builtin_amdgcn_readlane(r9, 1);
    const int b2 = __builtin_amdgcn_readlane(r9, 2);
    const int b3 = __builtin_amdgcn_readlane(r9, 3);
    const int b4 = __builtin_amdgcn_readlane(r9, 4);
    const int b5 = __builtin_amdgcn_readlane(r9, 5);
    const int b6 = __builtin_amdgcn_readlane(r9, 6);
    const int b7 = __builtin_amdgcn_readlane(r9, 7);
    const int b8 = __builtin_amdgcn_readlane(r9, 8);
    const int beg = b0, end = b8;

    auto invlen = [](int a, int bnd) {
        int l = bnd - a; return 1.0f / (float)(l > 1 ? l : 1);
    };
    const float il0 = invlen(b0, b1), il1 = invlen(b1, b2);
    const float il2 = invlen(b2, b3), il3 = invlen(b3, b4);
    const float il4 = invlen(b4, b5), il5 = invlen(b5, b6);
    const float il6 = invlen(b6, b7), il7 = invlen(b7, b8);

    const unsigned short* XWl = XW + lane;        // fold lane offset into base

    float acc = 0.f;
    int i = beg;
    while (i < end) {
        int m = end - i; if (m > 64) m = 64;
        int idx = i + lane; if (idx >= end) idx = end - 1;
        unsigned int ub = elist[idx];             // offset (coalesced, 1 load / 64 edges)
        float wb = il0;
        wb = (idx >= b1) ? il1 : wb;
        wb = (idx >= b2) ? il2 : wb;
        wb = (idx >= b3) ? il3 : wb;
        wb = (idx >= b4) ? il4 : wb;
        wb = (idx >= b5) ? il5 : wb;
        wb = (idx >= b6) ? il6 : wb;
        wb = (idx >= b7) ? il7 : wb;

        int j = 0;
        for (; j + 16 <= m; j += 16) {
            float vv[16], ww[16];
#pragma unroll
            for (int t = 0; t < 16; ++t) {
                unsigned int u = (unsigned int)__builtin_amdgcn_readlane((int)ub, j + t);
                ww[t] = rl_f(wb, j + t);
                vv[t] = bf2f(XWl[u]);
            }
#pragma unroll
            for (int t = 0; t < 16; ++t) acc += ww[t] * vv[t];
        }
        for (; j + 4 <= m; j += 4) {
            float vv[4], ww[4];
#pragma unroll
            for (int t = 0; t < 4; ++t) {
                unsigned int u = (unsigned int)__builtin_amdgcn_readlane((int)ub, j + t);
                ww[t] = rl_f(wb, j + t);
                vv[t] = bf2f(XWl[u]);
            }
#pragma unroll
            for (int t = 0; t < 4; ++t) acc += ww[t] * vv[t];
        }
        for (; j < m; ++j) {
            unsigned int u = (unsigned int)__builtin_amdgcn_readlane((int)ub, j);
            float w = rl_f(wb, j);
            acc += w * bf2f(XWl[u]);
        }
        i += m;
    }

    float res = acc + bf2f(XW[(size_t)n * WCOLS + 512 + lane]) + bias[lane];
    if (MODE == 0) {
        res = res > 0.f ? res : 0.f;
        ((unsigned short*)outp)[(size_t)n * 64 + lane] = f2bf(res);
    } else {
        ((float*)outp)[(size_t)n * 64 + lane] = res;
    }
}

// ---------------- launch ------------------------------------------------------
extern "C" void kernel_launch(void* const* d_in, const int* in_sizes, int n_in,
                              void* d_out, int out_size, void* d_ws, size_t ws_size,
                              hipStream_t stream) {
    const float* x     = (const float*)d_in[0];
    const int*   eidx  = (const int*)d_in[1];
    const int*   etyp  = (const int*)d_in[2];
    const float* W1    = (const float*)d_in[3];
    const float* root1 = (const float*)d_in[4];
    const float* b1    = (const float*)d_in[5];
    const float* W2    = (const float*)d_in[6];
    const float* root2 = (const float*)d_in[7];
    const float* b2    = (const float*)d_in[8];
    float*       out   = (float*)d_out;

    char* ws = (char*)d_ws;
    size_t off = 0;
    auto alloc = [&](size_t bytes) { char* p = ws + off; off += (bytes + 255) & ~(size_t)255; return p; };

    unsigned short* xW       = (unsigned short*)alloc((size_t)N_NODES * WCOLS * 2); // 115.2 MB (reused as hW)
    unsigned short* h        = (unsigned short*)alloc((size_t)N_NODES * HID * 2);   //  12.8 MB
    unsigned int*   elist    = (unsigned int*)alloc((size_t)N_EDGES * 4);           //  12.8 MB
    int*            rowstart8= (int*)alloc(((size_t)N_NODES * 8 + 1) * 4);          //   3.2 MB
    unsigned short* BT1      = (unsigned short*)alloc((size_t)WCOLS * C_IN * 2);
    unsigned short* BT2      = (unsigned short*)alloc((size_t)WCOLS * HID * 2);
    // total ~144.5 MB

    // sort scratch aliases into xW (dead before gemm_l1 writes xW)
    unsigned int* esort   = (unsigned int*)xW;                          // 12.8 MB
    int*          bcountT = (int*)((char*)xW + (size_t)N_EDGES * 4);    //  0.5 MB
    int*          lstartT = bcountT + NCELL;                            //  0.5 MB

    const int* srcp = eidx;
    const int* dstp = eidx + N_EDGES;

    // CSR build (weight prep folded into sort)
    edge_sort_local<<<NBLK, 1024, 0, stream>>>(srcp, dstp, etyp,
                                               W1, root1, W2, root2, BT1, BT2,
                                               esort, bcountT, lstartT);
    bucket_build<<<NBUCK, 1024, 0, stream>>>(esort, bcountT, lstartT, elist, rowstart8);

    const int gemm_grid = (N_NODES + 127) / 128;   // 782
    const int agg_grid  = N_NODES / 4;             // 25000

    // layer 1: x (f32) -> xW (bf16) -> h (bf16, relu)
    gemm_l1<<<gemm_grid, 512, 0, stream>>>(x, BT1, xW, N_NODES);
    agg_fused<0><<<agg_grid, 256, 0, stream>>>(xW, elist, rowstart8, b1, (void*)h);

    // layer 2: h -> hW (reuse xW) -> out (f32)
    gemm_l2<<<gemm_grid, 512, 0, stream>>>(h, BT2, xW, N_NODES);
    agg_fused<1><<<agg_grid, 256, 0, stream>>>(xW, elist, rowstart8, b2, (void*)out);
}

// Round 12
// 357.427 us; speedup vs baseline: 1.0456x; 1.0166x over previous
//
#include <hip/hip_runtime.h>

#define N_NODES 100000
#define N_EDGES 3200000
#define R_REL   8
#define C_IN    128
#define HID     64
#define WCOLS   576   // 8 relations * 64 + 64 (root slot)

// counting-sort parameters
#define NBUCK 500     // dst buckets
#define NPB   200     // nodes per bucket (500*200 = N)
#define NBLK  256     // edge chunks (runs: CHUNK/NBUCK = 25 edges = 100 B)
#define CHUNK 12500   // E / NBLK (exact)
#define NCELL (NBUCK * NBLK)   // 128000
#define BCAP  12288   // bucket emit cap (mean 6400, +73 sigma; 48 KB LDS)
#define PREPC 432     // prep elems per sort block (256*432 = 110592 = WCOLS*(C_IN+HID))
#define EPT   13      // edges per thread in sort (ceil(12500/1024))

typedef __attribute__((ext_vector_type(8))) short  short8;
typedef __attribute__((ext_vector_type(4))) float  float4v;

__device__ __forceinline__ float bf2f(unsigned short u) {
    union { unsigned int i; float f; } v; v.i = ((unsigned int)u) << 16; return v.f;
}
__device__ __forceinline__ unsigned short f2bf(float f) {
    union { float f; unsigned int i; } v; v.f = f;
    unsigned int r = v.i + 0x7FFFu + ((v.i >> 16) & 1u);   // RNE
    return (unsigned short)(r >> 16);
}
__device__ __forceinline__ float rl_f(float v, int j) {
    union { float f; int i; } a, b; a.f = v;
    b.i = __builtin_amdgcn_readlane(a.i, j);
    return b.f;
}

// exclusive scan of v across 1024 threads via shfl wave-scans (3 barriers).
__device__ __forceinline__ int block_exscan_1024(int v, int tid, int* wsum, int* tot) {
    __syncthreads();                       // protect wsum reuse
    const int lane = tid & 63, wid = tid >> 6;
    int s = v;
#pragma unroll
    for (int d = 1; d < 64; d <<= 1) {
        int t = __shfl_up(s, d, 64);
        if (lane >= d) s += t;
    }
    if (lane == 63) wsum[wid] = s;
    __syncthreads();
    if (wid == 0) {
        int ws = (lane < 16) ? wsum[lane] : 0;
#pragma unroll
        for (int d = 1; d < 16; d <<= 1) {
            int t = __shfl_up(ws, d, 64);
            if (lane >= d) ws += t;
        }
        if (lane < 16) wsum[lane] = ws;    // inclusive wave partials
    }
    __syncthreads();
    int wexcl = (wid == 0) ? 0 : wsum[wid - 1];
    if (tot) *tot = wsum[15];
    return wexcl + s - v;
}

// ---------------- K1: per-block counting sort, edges reg-cached --------------
// Reads each edge ONCE (13/thread into regs), histograms + scatters from regs.
__global__ __launch_bounds__(1024)
void edge_sort_local(const int* __restrict__ src, const int* __restrict__ dst,
                     const int* __restrict__ et,
                     const float* __restrict__ W1, const float* __restrict__ root1,
                     const float* __restrict__ W2, const float* __restrict__ root2,
                     unsigned short* __restrict__ BT1, unsigned short* __restrict__ BT2,
                     unsigned int* __restrict__ esort,
                     int* __restrict__ bcountT, int* __restrict__ lstartT) {
    __shared__ int cnt[NBUCK], cur[NBUCK], wsum[16];
    __shared__ unsigned int sedge[CHUNK];               // 50 KB
    const int blk = blockIdx.x, tid = threadIdx.x;
    const int e0 = blk * CHUNK;

    // folded weight prep: 432 elems per block, exact cover of 110592
    if (tid < PREPC) {
        int idx = blk * PREPC + tid;
        const int T1 = WCOLS * C_IN;          // 73728
        if (idx < T1) {
            int c = idx / C_IN, k = idx % C_IN;
            float v;
            if (c < 512) { int r = c >> 6, h = c & 63; v = W1[r * (C_IN * 64) + k * 64 + h]; }
            else         { v = root1[k * 64 + (c - 512)]; }
            BT1[idx] = f2bf(v);
        } else {
            int j = idx - T1;
            int c = j / HID, k = j % HID;
            float v;
            if (c < 512) { int r = c >> 6, h = c & 63; v = W2[r * (HID * 64) + k * 64 + h]; }
            else         { v = root2[k * 64 + (c - 512)]; }
            BT2[j] = f2bf(v);
        }
    }

    for (int i = tid; i < NBUCK; i += 1024) cnt[i] = 0;
    __syncthreads();

    // single read of all edge data into registers + histogram
    int db[EPT];
    unsigned int pk[EPT];
#pragma unroll
    for (int k = 0; k < EPT; ++k) {
        int idx = k * 1024 + tid;
        if (idx < CHUNK) {
            int d = dst[e0 + idx];
            int b = d / NPB;
            db[k] = b;
            pk[k] = ((unsigned int)src[e0 + idx] << 11) |
                    ((unsigned int)(d - b * NPB) << 3) | (unsigned int)et[e0 + idx];
            atomicAdd(&cnt[b], 1);
        } else db[k] = -1;
    }
    __syncthreads();

    int v = (tid < NBUCK) ? cnt[tid] : 0;
    int ex = block_exscan_1024(v, tid, wsum, nullptr);
    if (tid < NBUCK) {
        cur[tid] = ex;
        bcountT[blk * NBUCK + tid] = v;
        lstartT[blk * NBUCK + tid] = ex;
    }
    __syncthreads();     // cur stable before scatter atomics

    // scatter from regs (no second global read)
#pragma unroll
    for (int k = 0; k < EPT; ++k) {
        if (db[k] >= 0) {
            int pos = atomicAdd(&cur[db[k]], 1);
            sedge[pos] = pk[k];
        }
    }
    __syncthreads();
    for (int i = tid; i < CHUNK; i += 1024) esort[e0 + i] = sedge[i];
}

// ---------------- bucket_build v7: no input staging (4 LDS ops/edge) ---------
// pass 1 reads esort runs from global + histograms (no sedge copy);
// pass 2 RE-reads esort (L2-hot, each block's 25 KB slice) and emits into
// selist; flat coalesced copy-out. LDS ~67 KB -> 2 blocks/CU.
__global__ __launch_bounds__(1024)
void bucket_build(const unsigned int* __restrict__ esort,
                  const int* __restrict__ bcountT, const int* __restrict__ lstartT,
                  unsigned int* __restrict__ elist,
                  int* __restrict__ rowstart8) {
    __shared__ int   cnt[2048], cur[2048];              // 16384 B
    __shared__ int   rlen_s[NBLK], rpos[NBLK], wsum[16];  // 2112 B
    __shared__ unsigned int selist[BCAP];               // 49152 B  (total ~67 KB)

    const int b = blockIdx.x, tid = threadIdx.x;

    for (int i = tid; i < 2048; i += 1024) cnt[i] = 0;
    int myrl = 0, myls = 0;
    if (tid < NBLK) {
        myrl = bcountT[tid * NBUCK + b];
        myls = lstartT[tid * NBUCK + b];
        rlen_s[tid] = myrl;
        rpos[tid] = tid * CHUNK + myls;
    }

    int total;
    (void)block_exscan_1024(myrl, tid, wsum, &total);

    // seg0 = sum of per-block local prefixes == global exclusive prefix of b
    int seg0;
    (void)block_exscan_1024(myls, tid, wsum, &seg0);
    __syncthreads();                     // rlen_s/rpos visible
    const bool fits = (total <= BCAP);   // +73 sigma — effectively never false

    // ---- pass 1: run-assigned (4 thr/run) histogram only ----
    {
        const int run = tid >> 2, sub = tid & 3;
        const int len = rlen_s[run], lp = rpos[run];
        for (int k = sub; k < len; k += 4) {
            unsigned int e = esort[lp + k];
            atomicAdd(&cnt[(int)((e >> 3) & 255u) * 8 + (int)(e & 7u)], 1);
        }
    }
    __syncthreads();

    // ---- exclusive scan over 2048 counters: 2/thread + wave scan ----
    int base = tid * 2;
    int c0 = cnt[base], c1 = cnt[base + 1];
    int ex2 = block_exscan_1024(c0 + c1, tid, wsum, nullptr);
    cur[base] = ex2; cur[base + 1] = ex2 + c0;
    __syncthreads();

    // ---- per-(node,rel) boundary table ----
    for (int i = tid; i < NPB * 8; i += 1024)
        rowstart8[(b * NPB) * 8 + i] = seg0 + cur[i];
    if (b == NBUCK - 1 && tid == 0) rowstart8[N_NODES * 8] = N_EDGES;
    __syncthreads();                     // cur reads done before emit atomics

    // ---- pass 2: re-read esort (L2-hot), emit into LDS selist ----
    {
        const int run = tid >> 2, sub = tid & 3;
        const int len = rlen_s[run], lp = rpos[run];
        for (int k = sub; k < len; k += 4) {
            unsigned int e = esort[lp + k];
            int r = (int)(e & 7u);
            int j = (int)((e >> 3) & 255u) * 8 + r;
            int p = atomicAdd(&cur[j], 1);
            unsigned int eo = (e >> 11) * WCOLS + (unsigned int)(r * 64);
            if (fits) selist[p] = eo;
            else      elist[seg0 + p] = eo;
        }
    }
    __syncthreads();

    if (fits) {
        for (int i = tid; i < total; i += 1024)
            elist[seg0 + i] = selist[i];
    }
}

// ---------------- gemm_l1: xW[N][576] = x[N][128] @ BT1, dbuf B --------------
__global__ __launch_bounds__(512)
void gemm_l1(const float* __restrict__ A,
             const unsigned short* __restrict__ BT,
             unsigned short* __restrict__ Out, int nrows) {
    constexpr int K = C_IN;             // 128
    constexpr int LDB = K + 8;          // 136
    __shared__ __align__(16) unsigned short Blds[2][64 * LDB];  // 34.8 KB
    __shared__ __align__(16) unsigned short stage[8][16 * 64];  // 16 KB

    const int wave = threadIdx.x >> 6, lane = threadIdx.x & 63;
    const int l15 = lane & 15, quad = lane >> 4;
    const int rowbase = blockIdx.x * 128 + wave * 16;
    int arow = rowbase + l15;
    if (arow >= nrows) arow = nrows - 1;

    short8 afrag[4];
#pragma unroll
    for (int ks = 0; ks < 4; ++ks) {
        const float* p = A + (size_t)arow * K + ks * 32 + quad * 8;
        float4v u0 = *(const float4v*)p;
        float4v u1 = *(const float4v*)(p + 4);
        short8 f;
        f[0] = (short)f2bf(u0[0]); f[1] = (short)f2bf(u0[1]);
        f[2] = (short)f2bf(u0[2]); f[3] = (short)f2bf(u0[3]);
        f[4] = (short)f2bf(u1[0]); f[5] = (short)f2bf(u1[1]);
        f[6] = (short)f2bf(u1[2]); f[7] = (short)f2bf(u1[3]);
        afrag[ks] = f;
    }

    for (int i = threadIdx.x; i < 1024; i += 512) {
        int r = i >> 4, c = (i & 15) * 8;
        *(uint4*)&Blds[0][r * LDB + c] = *(const uint4*)(BT + r * K + c);
    }
    __syncthreads();

    int cur = 0;
    for (int chunk = 0; chunk < 9; ++chunk) {
        uint4 p0, p1;
        const int i0 = threadIdx.x, i1 = threadIdx.x + 512;
        if (chunk < 8) {
            const unsigned short* src = BT + (size_t)(chunk + 1) * 64 * K;
            p0 = *(const uint4*)(src + (i0 >> 4) * K + (i0 & 15) * 8);
            p1 = *(const uint4*)(src + (i1 >> 4) * K + (i1 & 15) * 8);
        }

        float4v acc[4];
#pragma unroll
        for (int ct = 0; ct < 4; ++ct) { acc[ct][0] = 0.f; acc[ct][1] = 0.f; acc[ct][2] = 0.f; acc[ct][3] = 0.f; }
#pragma unroll
        for (int ct = 0; ct < 4; ++ct)
#pragma unroll
            for (int ks = 0; ks < 4; ++ks) {
                short8 bfrag = *(const short8*)(&Blds[cur][(ct * 16 + l15) * LDB + ks * 32 + quad * 8]);
                acc[ct] = __builtin_amdgcn_mfma_f32_16x16x32_bf16(afrag[ks], bfrag, acc[ct], 0, 0, 0);
            }

#pragma unroll
        for (int ct = 0; ct < 4; ++ct)
#pragma unroll
            for (int r = 0; r < 4; ++r)
                stage[wave][(quad * 4 + r) * 64 + ct * 16 + l15] = f2bf(acc[ct][r]);
        {
            int r = lane >> 2, j = lane & 3;
            int orow = rowbase + r;
            if (orow < nrows) {
#pragma unroll
                for (int p = 0; p < 2; ++p) {
                    int c0 = (j + p * 4) * 8;
                    uint4 v = *(const uint4*)&stage[wave][r * 64 + c0];
                    *(uint4*)(Out + (size_t)orow * WCOLS + chunk * 64 + c0) = v;
                }
            }
        }

        if (chunk < 8) {
            *(uint4*)&Blds[cur ^ 1][(i0 >> 4) * LDB + (i0 & 15) * 8] = p0;
            *(uint4*)&Blds[cur ^ 1][(i1 >> 4) * LDB + (i1 & 15) * 8] = p1;
            cur ^= 1;
        }
        __syncthreads();
    }
}

// ---------------- gemm_l2: hW[N][576] = h[N][64] @ BT2, per-chunk dbuf -------
__global__ __launch_bounds__(512)
void gemm_l2(const unsigned short* __restrict__ A,     // h [N][64]
             const unsigned short* __restrict__ BT,    // [576][64]
             unsigned short* __restrict__ Out, int nrows) {
    constexpr int K = HID;              // 64
    constexpr int LDB = K + 8;          // 72
    __shared__ __align__(16) unsigned short Blds[2][64 * LDB];  // 18.4 KB
    __shared__ __align__(16) unsigned short stage[8][16 * 64];  // 16 KB

    const int wave = threadIdx.x >> 6, lane = threadIdx.x & 63;
    const int l15 = lane & 15, quad = lane >> 4;
    const int rowbase = blockIdx.x * 128 + wave * 16;
    int arow = rowbase + l15;
    if (arow >= nrows) arow = nrows - 1;

    short8 afrag[2];
#pragma unroll
    for (int ks = 0; ks < 2; ++ks)
        afrag[ks] = *(const short8*)(A + (size_t)arow * K + ks * 32 + quad * 8);

    {   // preload chunk 0: 512 vectors of 16B, one per thread
        int r = threadIdx.x >> 3, c = (threadIdx.x & 7) * 8;
        *(uint4*)&Blds[0][r * LDB + c] = *(const uint4*)(BT + r * K + c);
    }
    __syncthreads();

    int cur = 0;
    for (int chunk = 0; chunk < 9; ++chunk) {
        uint4 p0;
        if (chunk < 8) {
            const unsigned short* src = BT + (size_t)(chunk + 1) * 64 * K;
            p0 = *(const uint4*)(src + (threadIdx.x >> 3) * K + (threadIdx.x & 7) * 8);
        }

        float4v acc[4];
#pragma unroll
        for (int ct = 0; ct < 4; ++ct) { acc[ct][0] = 0.f; acc[ct][1] = 0.f; acc[ct][2] = 0.f; acc[ct][3] = 0.f; }
#pragma unroll
        for (int ct = 0; ct < 4; ++ct)
#pragma unroll
            for (int ks = 0; ks < 2; ++ks) {
                short8 bfrag = *(const short8*)(&Blds[cur][(ct * 16 + l15) * LDB + ks * 32 + quad * 8]);
                acc[ct] = __builtin_amdgcn_mfma_f32_16x16x32_bf16(afrag[ks], bfrag, acc[ct], 0, 0, 0);
            }

#pragma unroll
        for (int ct = 0; ct < 4; ++ct)
#pragma unroll
            for (int r = 0; r < 4; ++r)
                stage[wave][(quad * 4 + r) * 64 + ct * 16 + l15] = f2bf(acc[ct][r]);
        {
            int r = lane >> 2, j = lane & 3;
            int orow = rowbase + r;
            if (orow < nrows) {
#pragma unroll
                for (int p = 0; p < 2; ++p) {
                    int c0 = (j + p * 4) * 8;
                    uint4 v = *(const uint4*)&stage[wave][r * 64 + c0];
                    *(uint4*)(Out + (size_t)orow * WCOLS + chunk * 64 + c0) = v;
                }
            }
        }

        if (chunk < 8) {
            *(uint4*)&Blds[cur ^ 1][(threadIdx.x >> 3) * LDB + (threadIdx.x & 7) * 8] = p0;
            cur ^= 1;
        }
        __syncthreads();
    }
}

// ---------------- fused CSR aggregate + root + bias (+relu) ------------------
template <int MODE>   // 0: relu -> bf16 h ; 1: -> f32 out
__global__ __launch_bounds__(256)
void agg_fused(const unsigned short* __restrict__ XW,
               const unsigned int* __restrict__ elist,
               const int* __restrict__ rowstart8,
               const float* __restrict__ bias,
               void* __restrict__ outp) {
    const int wave = threadIdx.x >> 6, lane = threadIdx.x & 63;
    const int n = blockIdx.x * 4 + wave;          // grid covers N exactly
    int r9 = 0;
    if (lane < 9) r9 = rowstart8[n * 8 + lane];
    const int b0 = __builtin_amdgcn_readlane(r9, 0);
    const int b1 = __builtin_amdgcn_readlane(r9, 1);
    const int b2 = __builtin_amdgcn_readlane(r9, 2);
    const int b3 = __builtin_amdgcn_readlane(r9, 3);
    const int b4 = __builtin_amdgcn_readlane(r9, 4);
    const int b5 = __builtin_amdgcn_readlane(r9, 5);
    const int b6 = __builtin_amdgcn_readlane(r9, 6);
    const int b7 = __builtin_amdgcn_readlane(r9, 7);
    const int b8 = __builtin_amdgcn_readlane(r9, 8);
    const int beg = b0, end = b8;

    auto invlen = [](int a, int bnd) {
        int l = bnd - a; return 1.0f / (float)(l > 1 ? l : 1);
    };
    const float il0 = invlen(b0, b1), il1 = invlen(b1, b2);
    const float il2 = invlen(b2, b3), il3 = invlen(b3, b4);
    const float il4 = invlen(b4, b5), il5 = invlen(b5, b6);
    const float il6 = invlen(b6, b7), il7 = invlen(b7, b8);

    const unsigned short* XWl = XW + lane;        // fold lane offset into base

    float acc = 0.f;
    int i = beg;
    while (i < end) {
        int m = end - i; if (m > 64) m = 64;
        int idx = i + lane; if (idx >= end) idx = end - 1;
        unsigned int ub = elist[idx];             // offset (coalesced, 1 load / 64 edges)
        float wb = il0;
        wb = (idx >= b1) ? il1 : wb;
        wb = (idx >= b2) ? il2 : wb;
        wb = (idx >= b3) ? il3 : wb;
        wb = (idx >= b4) ? il4 : wb;
        wb = (idx >= b5) ? il5 : wb;
        wb = (idx >= b6) ? il6 : wb;
        wb = (idx >= b7) ? il7 : wb;

        int j = 0;
        for (; j + 16 <= m; j += 16) {
            float vv[16], ww[16];
#pragma unroll
            for (int t = 0; t < 16; ++t) {
                unsigned int u = (unsigned int)__builtin_amdgcn_readlane((int)ub, j + t);
                ww[t] = rl_f(wb, j + t);
                vv[t] = bf2f(XWl[u]);
            }
#pragma unroll
            for (int t = 0; t < 16; ++t) acc += ww[t] * vv[t];
        }
        for (; j + 4 <= m; j += 4) {
            float vv[4], ww[4];
#pragma unroll
            for (int t = 0; t < 4; ++t) {
                unsigned int u = (unsigned int)__builtin_amdgcn_readlane((int)ub, j + t);
                ww[t] = rl_f(wb, j + t);
                vv[t] = bf2f(XWl[u]);
            }
#pragma unroll
            for (int t = 0; t < 4; ++t) acc += ww[t] * vv[t];
        }
        for (; j < m; ++j) {
            unsigned int u = (unsigned int)__builtin_amdgcn_readlane((int)ub, j);
            float w = rl_f(wb, j);
            acc += w * bf2f(XWl[u]);
        }
        i += m;
    }

    float res = acc + bf2f(XW[(size_t)n * WCOLS + 512 + lane]) + bias[lane];
    if (MODE == 0) {
        res = res > 0.f ? res : 0.f;
        ((unsigned short*)outp)[(size_t)n * 64 + lane] = f2bf(res);
    } else {
        ((float*)outp)[(size_t)n * 64 + lane] = res;
    }
}

// ---------------- launch ------------------------------------------------------
extern "C" void kernel_launch(void* const* d_in, const int* in_sizes, int n_in,
                              void* d_out, int out_size, void* d_ws, size_t ws_size,
                              hipStream_t stream) {
    const float* x     = (const float*)d_in[0];
    const int*   eidx  = (const int*)d_in[1];
    const int*   etyp  = (const int*)d_in[2];
    const float* W1    = (const float*)d_in[3];
    const float* root1 = (const float*)d_in[4];
    const float* b1    = (const float*)d_in[5];
    const float* W2    = (const float*)d_in[6];
    const float* root2 = (const float*)d_in[7];
    const float* b2    = (const float*)d_in[8];
    float*       out   = (float*)d_out;

    char* ws = (char*)d_ws;
    size_t off = 0;
    auto alloc = [&](size_t bytes) { char* p = ws + off; off += (bytes + 255) & ~(size_t)255; return p; };

    unsigned short* xW       = (unsigned short*)alloc((size_t)N_NODES * WCOLS * 2); // 115.2 MB (reused as hW)
    unsigned short* h        = (unsigned short*)alloc((size_t)N_NODES * HID * 2);   //  12.8 MB
    unsigned int*   elist    = (unsigned int*)alloc((size_t)N_EDGES * 4);           //  12.8 MB
    int*            rowstart8= (int*)alloc(((size_t)N_NODES * 8 + 1) * 4);          //   3.2 MB
    unsigned short* BT1      = (unsigned short*)alloc((size_t)WCOLS * C_IN * 2);
    unsigned short* BT2      = (unsigned short*)alloc((size_t)WCOLS * HID * 2);
    // total ~144.5 MB

    // sort scratch aliases into xW (dead before gemm_l1 writes xW)
    unsigned int* esort   = (unsigned int*)xW;                          // 12.8 MB
    int*          bcountT = (int*)((char*)xW + (size_t)N_EDGES * 4);    //  0.5 MB
    int*          lstartT = bcountT + NCELL;                            //  0.5 MB

    const int* srcp = eidx;
    const int* dstp = eidx + N_EDGES;

    // CSR build (weight prep folded into sort)
    edge_sort_local<<<NBLK, 1024, 0, stream>>>(srcp, dstp, etyp,
                                               W1, root1, W2, root2, BT1, BT2,
                                               esort, bcountT, lstartT);
    bucket_build<<<NBUCK, 1024, 0, stream>>>(esort, bcountT, lstartT, elist, rowstart8);

    const int gemm_grid = (N_NODES + 127) / 128;   // 782
    const int agg_grid  = N_NODES / 4;             // 25000

    // layer 1: x (f32) -> xW (bf16) -> h (bf16, relu)
    gemm_l1<<<gemm_grid, 512, 0, stream>>>(x, BT1, xW, N_NODES);
    agg_fused<0><<<agg_grid, 256, 0, stream>>>(xW, elist, rowstart8, b1, (void*)h);

    // layer 2: h -> hW (reuse xW) -> out (f32)
    gemm_l2<<<gemm_grid, 512, 0, stream>>>(h, BT2, xW, N_NODES);
    agg_fused<1><<<agg_grid, 256, 0, stream>>>(xW, elist, rowstart8, b2, (void*)out);
}